// Round 8
// baseline (287.717 us; speedup 1.0000x reference)
//
#include <hip/hip_runtime.h>

// iRPE contextual/transposed PRODUCT, round-13: ZERO-WAIT + HIGH TLP.
//
// r12 (zero-wait, 8 waves/CU) = 286us, best so far, but still ~2.2 TB/s.
// Unified model of r5-r12: in-order wave issue means a wave stalled on
// store backpressure issues NOTHING (its GEMV included); with 8 waves/CU
// there is no other resident work, so drain time is exposed. The fill
// survives at 3 waves/CU only because its waves have nothing else to do;
// r10 (23 waves/CU, stores never waited) hid the whole drain under spin.
// r13 = r12's exact zero-wait structure (W in regs, wave-private LDS x,
// lt in lane registers, shfl gather, no barriers, no in-loop global loads)
// with ONE variable changed: 2048 blocks x 8 rows/wave (target ~20
// waves/CU) instead of 512 x 32.
//
// GEMV keeps the exact d-ascending fmaf chain -> bit-identical (absmax 0).

constexpr int cL = 1024;
constexpr int cD = 64;
constexpr int cK = 49;
constexpr int cRW = 8;    // rows per wave (was 32)

typedef float vf4 __attribute__((ext_vector_type(4)));

// piecewise_index(d) + BETA_INT for this config (verified absmax 0.0)
__device__ __forceinline__ int bucket_c(int d) {
    int a = d < 0 ? -d : d;
    int m = a < 4 ? a : 4;     // min(|d|,4)
    m -= (m >= 3) ? 1 : 0;     // q(|d|) = {0,1,2,2,3,3,...}
    int p = d < 0 ? -m : m;
    return p + 3;
}

__global__ __launch_bounds__(256) void irpe_wavestream_hi(
    const float* __restrict__ x,   // (bh, i, d)
    const float* __restrict__ W,   // (h, d, k)
    float*       __restrict__ out) // (bh, i, j)
{
    __shared__ float xw[4][cRW * cD];    // 4 waves x 2 KB, wave-private

    const int gid  = blockIdx.x;         // 2048 blocks
    const int bh   = gid & 63;
    const int seg  = gid >> 6;           // 0..31
    const int tid  = threadIdx.x;
    const int w    = tid >> 6;           // wave 0..3
    const int lane = tid & 63;
    const int i0w  = seg * 32 + w * cRW; // this wave's 8 rows
    const int h    = bh & 7;

    // ---- one-time: this lane's W column into registers ----
    const int klane = lane < cK ? lane : lane - cK;   // lanes 49-63: dup k
    float wreg[cD];
    const float* wcol = W + (size_t)h * cD * cK + klane;
    #pragma unroll
    for (int d = 0; d < cD; ++d) wreg[d] = wcol[(size_t)d * cK];

    // ---- one-time: stage this wave's 8 x-rows into its LDS region ----
    vf4*       xw4  = (vf4*)xw[w];
    const vf4* xsrc = (const vf4*)(x + ((size_t)bh * cL + i0w) * cD);
    #pragma unroll
    for (int r = 0; r < 2; ++r) xw4[r * 64 + lane] = xsrc[r * 64 + lane];
    // (same wave writes & reads its region: lgkmcnt ordering, no barrier)

    // per-lane store-side constants
    const int xj = (lane * 4) & 31;      // (lane*4+cc)&31 = xj+cc
    const int l8 = lane >> 3;            // yj = s*8 + l8

    const float* xrow  = xw[w];
    vf4*         obase = (vf4*)(out + ((size_t)bh * cL + i0w) * cL);

    #pragma unroll
    for (int rp = 0; rp < cRW; rp += 2) {
        // GEMV rows rp, rp+1: two interleaved chains, d ascending
        // (exact fmaf order of r5-r12 -> bit-identical lt)
        float a0 = 0.0f, a1 = 0.0f;
        const vf4* xr0 = (const vf4*)(xrow + (rp + 0) * cD);
        const vf4* xr1 = (const vf4*)(xrow + (rp + 1) * cD);
        #pragma unroll
        for (int dq = 0; dq < cD / 4; ++dq) {
            vf4 v0 = xr0[dq];            // all lanes same addr: broadcast
            vf4 v1 = xr1[dq];
            #pragma unroll
            for (int u = 0; u < 4; ++u) {
                a0 = fmaf(v0[u], wreg[dq * 4 + u], a0);
                a1 = fmaf(v1[u], wreg[dq * 4 + u], a1);
            }
        }
        // gather (register shuffle) + fire-and-forget stores
        #pragma unroll
        for (int rr = 0; rr < 2; ++rr) {
            const int   i   = i0w + rp + rr;
            const float acc = rr ? a1 : a0;
            const int   yi  = i >> 5;
            const int   xi  = i & 31;
            const int   bse = xi - xj;
            int cb[4];
            #pragma unroll
            for (int cc = 0; cc < 4; ++cc) cb[cc] = bucket_c(bse - cc);
            #pragma unroll
            for (int s = 0; s < 4; ++s) {
                const int rb = 7 * bucket_c(yi - (s * 8 + l8));
                vf4 o;
                o.x = __shfl(acc, rb + cb[0], 64);
                o.y = __shfl(acc, rb + cb[1], 64);
                o.z = __shfl(acc, rb + cb[2], 64);
                o.w = __shfl(acc, rb + cb[3], 64);
                obase[(size_t)(rp + rr) * (cL / 4) + s * 64 + lane] = o;
            }
        }
    }
}

extern "C" void kernel_launch(void* const* d_in, const int* in_sizes, int n_in,
                              void* d_out, int out_size, void* d_ws, size_t ws_size,
                              hipStream_t stream) {
    const float* x   = (const float*)d_in[0];   // (8,8,1024,64) fp32
    const float* W   = (const float*)d_in[1];   // (8,64,49) fp32
    float*       out = (float*)d_out;           // (8,8,1024,1024) fp32

    const int grid = 64 * 32;                   // 2048 blocks, ~8 per CU
    irpe_wavestream_hi<<<grid, 256, 0, stream>>>(x, W, out);
}